// Round 10
// baseline (1076.025 us; speedup 1.0000x reference)
//
#include <hip/hip_runtime.h>
#include <hip/hip_fp16.h>
#include <math.h>

// Problem constants: B=8, Tt=16, C=1, H=W=512, 4 in-channels, 10 T-planes.
#define Bd 8
#define Td 16
#define Hd 512
#define Wd 512
#define HWc (Hd * Wd)          // 262144
#define NPIX (Bd * HWc)        // 2,097,152

// ---------------- conv tiling: 128x8 tile, 2 px/thread, 512 threads ----------
#define CTW 128
#define CTH 8
#define CRW 130
#define CRH 10
#define CPITCH 132
#define CTHR 512

// ---------------- fused-step tiling: 128x64 core, halo 6, in-place LDS -------
#define FCR 128                // core rows
#define FCC 64                 // core cols
#define FH  6                  // halo
#define FTR 140                // region rows = FCR + 2*FH
#define FTC 76                 // region cols = FCC + 2*FH
#define FLP 77                 // LDS row pitch (words)
#define FTHR 1024
#define FRPG 11                // owned rows per thread
#define FNG 13                 // row groups (13*11 = 143 >= 138 interior rows)

// ---------------------------------------------------------------------------
// Kernel 1: tiled conv  T = conv2d(x[:, -4:, 0], W_unet, SAME) + b_unet,
// fused with xt0 = stencil(x[:,15,0], T_fp32) -> out[:, 0].
// T stored as half2 pairs: plane q holds (T[2q], T[2q+1]); layout (B,5,H,W).
// ---------------------------------------------------------------------------
__global__ __launch_bounds__(CTHR)
void conv_step0_kernel(const float* __restrict__ x,
                       const float* __restrict__ Wu,
                       const float* __restrict__ bu,
                       __half2* __restrict__ T,
                       float* __restrict__ out) {
    __shared__ __align__(16) float sX[4][CRH][CPITCH];

    int bx  = blockIdx.x;           // 2048 = 8 b * 64 row-bands * 4 col-bands
    int b   = bx >> 8;
    int rem = bx & 255;
    int by  = rem >> 2;
    int bc  = rem & 3;
    int i0  = by * CTH;
    int j0  = bc * CTW;

    const float* xb = x + ((size_t)b * Td + 12) * HWc;
    int tid = threadIdx.x;

    for (int idx = tid; idx < 4 * CRH * CRW; idx += CTHR) {
        int ch = idx / (CRH * CRW);
        int r2 = idx - ch * (CRH * CRW);
        int r  = r2 / CRW;
        int c  = r2 - r * CRW;
        int gi = i0 + r - 1, gj = j0 + c - 1;
        float v = 0.0f;
        if ((unsigned)gi < (unsigned)Hd && (unsigned)gj < (unsigned)Wd)
            v = xb[(size_t)ch * HWc + gi * Wd + gj];
        sX[ch][r][c] = v;
    }
    __syncthreads();

    int tx = tid & 63;              // pixel pair: cols 2tx, 2tx+1
    int ty = tid >> 6;              // tile row 0..7

    float t0[10], t1[10];
    #pragma unroll
    for (int o = 0; o < 10; ++o) { float bv = bu[o]; t0[o] = bv; t1[o] = bv; }

    #pragma unroll
    for (int ch = 0; ch < 4; ++ch)
        #pragma unroll
        for (int kh = 0; kh < 3; ++kh) {
            const float* rp = &sX[ch][ty + kh][2 * tx];
            float2 a  = *(const float2*)rp;
            float2 b2 = *(const float2*)(rp + 2);
            float w0 = a.x, w1 = a.y, w2 = b2.x, w3 = b2.y;
            #pragma unroll
            for (int o = 0; o < 10; ++o) {
                float wt0 = Wu[((o * 4 + ch) * 3 + kh) * 3 + 0];
                float wt1 = Wu[((o * 4 + ch) * 3 + kh) * 3 + 1];
                float wt2 = Wu[((o * 4 + ch) * 3 + kh) * 3 + 2];
                t0[o] += w0 * wt0 + w1 * wt1 + w2 * wt2;
                t1[o] += w1 * wt0 + w2 * wt1 + w3 * wt2;
            }
        }

    int gi = i0 + ty;
    int gjv = j0 + 2 * tx;
    size_t pix = (size_t)gi * Wd + gjv;
    __half2* Tb = T + (size_t)b * 5 * HWc;
    #pragma unroll
    for (int q = 0; q < 5; ++q) {
        __half2 h0 = __floats2half2_rn(t0[2 * q], t0[2 * q + 1]);
        __half2 h1 = __floats2half2_rn(t1[2 * q], t1[2 * q + 1]);
        uint2 pk;
        pk.x = *(unsigned*)&h0;
        pk.y = *(unsigned*)&h1;
        *(uint2*)(Tb + (size_t)q * HWc + pix) = pk;
    }

    // step0 on channel 3 (slice 15), fp32 coefficients.
    float o0 = t0[9], o1 = t1[9];
    #pragma unroll
    for (int di = 0; di < 3; ++di) {
        const float* rp = &sX[3][ty + di][2 * tx];
        float2 a  = *(const float2*)rp;
        float2 b2 = *(const float2*)(rp + 2);
        float w0 = a.x, w1 = a.y, w2 = b2.x, w3 = b2.y;
        #pragma unroll
        for (int dj = 0; dj < 3; ++dj) {
            float xa = (dj == 0) ? w0 : ((dj == 1) ? w1 : w2);
            float xc = (dj == 0) ? w1 : ((dj == 1) ? w2 : w3);
            o0 += xa * t0[dj * 3 + di];
            o1 += xc * t1[dj * 3 + di];
        }
    }
    float2 ov; ov.x = o0; ov.y = o1;
    *(float2*)(out + (size_t)b * Td * HWc + pix) = ov;
}

// ---------------------------------------------------------------------------
// Kernel 2: one scan-body iteration = 6 fused stencil steps on a 128x64 core
// (region 140x76, halo 6). SINGLE in-place LDS buffer: per step, each thread
// computes its 11 owned rows into registers (streaming 3x3 window), barrier,
// writes back, barrier. T (55 half2/thread) register-resident; T-loads are
// issued before the stage loop so staging hides their latency.
// 256 blocks = 8 b * 4 row-tiles * 8 col-tiles -> exactly 1 block/CU, 1 round.
// Ring (r=0/139, c=0/75) never written -> stale; contamination moves <=1
// px/step inward; halo 6 keeps the 128x64 core clean. Out-of-image interior
// pixels forced to 0 every step (global zero-padding semantics).
// ---------------------------------------------------------------------------
__global__ __launch_bounds__(FTHR)
void fused6_bigtile_kernel(const float* __restrict__ xin,   // out slot t-1 base
                           const __half2* __restrict__ T,
                           float* __restrict__ xout) {      // out slot t base
    __shared__ float sA[FTR * FLP];   // 140*77*4 = 43120 B

    int tile = blockIdx.x;            // 256 = 8 b * 4 tr * 8 tc
    int b  = tile >> 5;
    int tr = (tile >> 3) & 3;
    int tc = tile & 7;
    int ri = tr * FCR - FH;
    int rj = tc * FCC - FH;

    const float* xb = xin + (size_t)b * Td * HWc;
    const __half2* Tb = T + (size_t)b * 5 * HWc;
    int tid = threadIdx.x;

    int g  = tid / FTC;               // 0..13 (13 = inactive tail)
    int c  = tid - g * FTC;           // 0..75
    int rs = 1 + g * FRPG;            // first owned row
    bool active = (g < FNG) && (c >= 1) && (c <= FTC - 2);
    int  gj     = rj + c;
    bool colin  = (unsigned)gj < (unsigned)Wd;

    // T coefficients first (fills the memory queue; stage loop below overlaps).
    __half2 treg[FRPG][5];
    #pragma unroll
    for (int jj = 0; jj < FRPG; ++jj) {
        int r  = rs + jj;
        int gi = ri + r;
        bool ok = active && (r <= FTR - 2) &&
                  ((unsigned)gi < (unsigned)Hd) && colin;
        #pragma unroll
        for (int q = 0; q < 5; ++q)
            treg[jj][q] = ok ? Tb[(size_t)q * HWc + gi * Wd + gj]
                             : __floats2half2_rn(0.0f, 0.0f);
    }

    // Stage the 140x76 region (zeros outside image).
    for (int idx = tid; idx < FTR * FTC; idx += FTHR) {
        int r = idx / FTC, cc = idx - r * FTC;
        int gi2 = ri + r, gj2 = rj + cc;
        float v = 0.0f;
        if ((unsigned)gi2 < (unsigned)Hd && (unsigned)gj2 < (unsigned)Wd)
            v = xb[gi2 * Wd + gj2];
        sA[r * FLP + cc] = v;
    }
    __syncthreads();

    #pragma unroll
    for (int s = 1; s <= 6; ++s) {
        float nv[FRPG];
        if (active) {
            // Streaming 3-col window over rows rs-1 .. rs+11 (clamped to region).
            float w00 = sA[(rs - 1) * FLP + c - 1];
            float w01 = sA[(rs - 1) * FLP + c];
            float w02 = sA[(rs - 1) * FLP + c + 1];
            float w10 = sA[rs * FLP + c - 1];
            float w11 = sA[rs * FLP + c];
            float w12 = sA[rs * FLP + c + 1];
            #pragma unroll
            for (int jj = 0; jj < FRPG; ++jj) {
                int r  = rs + jj;
                int r2 = (r + 1 <= FTR - 1) ? (r + 1) : (FTR - 1);  // clamp tail
                float w20 = sA[r2 * FLP + c - 1];
                float w21 = sA[r2 * FLP + c];
                float w22 = sA[r2 * FLP + c + 1];

                float2 p0 = __half22float2(treg[jj][0]);  // T0,T1
                float2 p1 = __half22float2(treg[jj][1]);  // T2,T3
                float2 p2 = __half22float2(treg[jj][2]);  // T4,T5
                float2 p3 = __half22float2(treg[jj][3]);  // T6,T7
                float2 p4 = __half22float2(treg[jj][4]);  // T8,T9

                // k = dj*3+di multiplies x[r+di-1][c+dj-1]
                float a = p4.y
                        + w00 * p0.x + w10 * p0.y + w20 * p1.x
                        + w01 * p1.y + w11 * p2.x + w21 * p2.y
                        + w02 * p3.x + w12 * p3.y + w22 * p4.x;
                if ((s & 1) == 0) a = 1.0f / (1.0f + __expf(-a));

                int gi2 = ri + r;
                bool inimg = ((unsigned)gi2 < (unsigned)Hd) && colin;
                nv[jj] = inimg ? a : 0.0f;

                w00 = w10; w01 = w11; w02 = w12;
                w10 = w20; w11 = w21; w12 = w22;
            }
        }
        __syncthreads();   // all reads of step s-1 state complete
        if (active) {
            #pragma unroll
            for (int jj = 0; jj < FRPG; ++jj) {
                int r = rs + jj;
                if (r <= FTR - 2) sA[r * FLP + c] = nv[jj];
            }
        }
        __syncthreads();   // all writes visible before next step's reads
    }

    // Write the 128x64 core (always fully inside the image).
    float* ob = xout + (size_t)b * Td * HWc;
    for (int idx = tid; idx < FCR * FCC; idx += FTHR) {
        int rr = idx >> 6, cc = idx & 63;
        ob[(ri + FH + rr) * Wd + (rj + FH + cc)] =
            sA[(FH + rr) * FLP + (FH + cc)];
    }
}

// ---------------------------------------------------------------------------
// Workspace: T only (B*5*H*W half2 = 40 MB).
// ---------------------------------------------------------------------------
extern "C" void kernel_launch(void* const* d_in, const int* in_sizes, int n_in,
                              void* d_out, int out_size, void* d_ws, size_t ws_size,
                              hipStream_t stream) {
    const float* x  = (const float*)d_in[0];
    const float* Wu = (const float*)d_in[1];
    const float* bu = (const float*)d_in[2];
    float* out = (float*)d_out;
    __half2* T = (__half2*)d_ws;

    conv_step0_kernel<<<2048, CTHR, 0, stream>>>(x, Wu, bu, T, out);

    for (int t = 1; t < Td; ++t)
        fused6_bigtile_kernel<<<256, FTHR, 0, stream>>>(out + (size_t)(t - 1) * HWc, T,
                                                        out + (size_t)t * HWc);
}

// Round 11
// 616.998 us; speedup vs baseline: 1.7440x; 1.7440x over previous
//
#include <hip/hip_runtime.h>
#include <hip/hip_fp16.h>
#include <math.h>

// Problem constants: B=8, Tt=16, C=1, H=W=512, 4 in-channels, 10 T-planes.
#define Bd 8
#define Td 16
#define Hd 512
#define Wd 512
#define HWc (Hd * Wd)          // 262144
#define NPIX (Bd * HWc)        // 2,097,152

// ---------------- conv tiling: 128x8 tile, 2 px/thread, 512 threads ----------
#define CTW 128
#define CTH 8
#define CRW 130
#define CRH 10
#define CPITCH 132
#define CTHR 512

// ---------------- fused-step tiling (round-7 proven geometry) ----------------
#define TS   64
#define H6   6
#define RS   76                // TS + 2*H6
#define LP   77                // LDS row pitch
#define NTHR 768
#define RPG  8                 // owned rows per thread
#define NG   10                // row groups

// ---------------------------------------------------------------------------
// Kernel 1: tiled conv  T = conv2d(x[:, -4:, 0], W_unet, SAME) + b_unet,
// fused with xt0 = stencil(x[:,15,0], T_fp32) -> out[:, 0].
// T stored as half2 pairs: plane q holds (T[2q], T[2q+1]); layout (B,5,H,W).
// ---------------------------------------------------------------------------
__global__ __launch_bounds__(CTHR)
void conv_step0_kernel(const float* __restrict__ x,
                       const float* __restrict__ Wu,
                       const float* __restrict__ bu,
                       __half2* __restrict__ T,
                       float* __restrict__ out) {
    __shared__ __align__(16) float sX[4][CRH][CPITCH];

    int bx  = blockIdx.x;           // 2048 = 8 b * 64 row-bands * 4 col-bands
    int b   = bx >> 8;
    int rem = bx & 255;
    int by  = rem >> 2;
    int bc  = rem & 3;
    int i0  = by * CTH;
    int j0  = bc * CTW;

    const float* xb = x + ((size_t)b * Td + 12) * HWc;
    int tid = threadIdx.x;

    for (int idx = tid; idx < 4 * CRH * CRW; idx += CTHR) {
        int ch = idx / (CRH * CRW);
        int r2 = idx - ch * (CRH * CRW);
        int r  = r2 / CRW;
        int c  = r2 - r * CRW;
        int gi = i0 + r - 1, gj = j0 + c - 1;
        float v = 0.0f;
        if ((unsigned)gi < (unsigned)Hd && (unsigned)gj < (unsigned)Wd)
            v = xb[(size_t)ch * HWc + gi * Wd + gj];
        sX[ch][r][c] = v;
    }
    __syncthreads();

    int tx = tid & 63;              // pixel pair: cols 2tx, 2tx+1
    int ty = tid >> 6;              // tile row 0..7

    float t0[10], t1[10];
    #pragma unroll
    for (int o = 0; o < 10; ++o) { float bv = bu[o]; t0[o] = bv; t1[o] = bv; }

    #pragma unroll
    for (int ch = 0; ch < 4; ++ch)
        #pragma unroll
        for (int kh = 0; kh < 3; ++kh) {
            const float* rp = &sX[ch][ty + kh][2 * tx];
            float2 a  = *(const float2*)rp;
            float2 b2 = *(const float2*)(rp + 2);
            float w0 = a.x, w1 = a.y, w2 = b2.x, w3 = b2.y;
            #pragma unroll
            for (int o = 0; o < 10; ++o) {
                float wt0 = Wu[((o * 4 + ch) * 3 + kh) * 3 + 0];
                float wt1 = Wu[((o * 4 + ch) * 3 + kh) * 3 + 1];
                float wt2 = Wu[((o * 4 + ch) * 3 + kh) * 3 + 2];
                t0[o] += w0 * wt0 + w1 * wt1 + w2 * wt2;
                t1[o] += w1 * wt0 + w2 * wt1 + w3 * wt2;
            }
        }

    int gi = i0 + ty;
    int gjv = j0 + 2 * tx;
    size_t pix = (size_t)gi * Wd + gjv;
    __half2* Tb = T + (size_t)b * 5 * HWc;
    #pragma unroll
    for (int q = 0; q < 5; ++q) {
        __half2 h0 = __floats2half2_rn(t0[2 * q], t0[2 * q + 1]);
        __half2 h1 = __floats2half2_rn(t1[2 * q], t1[2 * q + 1]);
        uint2 pk;
        pk.x = *(unsigned*)&h0;
        pk.y = *(unsigned*)&h1;
        *(uint2*)(Tb + (size_t)q * HWc + pix) = pk;
    }

    // step0 on channel 3 (slice 15), fp32 coefficients.
    float o0 = t0[9], o1 = t1[9];
    #pragma unroll
    for (int di = 0; di < 3; ++di) {
        const float* rp = &sX[3][ty + di][2 * tx];
        float2 a  = *(const float2*)rp;
        float2 b2 = *(const float2*)(rp + 2);
        float w0 = a.x, w1 = a.y, w2 = b2.x, w3 = b2.y;
        #pragma unroll
        for (int dj = 0; dj < 3; ++dj) {
            float xa = (dj == 0) ? w0 : ((dj == 1) ? w1 : w2);
            float xc = (dj == 0) ? w1 : ((dj == 1) ? w2 : w3);
            o0 += xa * t0[dj * 3 + di];
            o1 += xc * t1[dj * 3 + di];
        }
    }
    float2 ov; ov.x = o0; ov.y = o1;
    *(float2*)(out + (size_t)b * Td * HWc + pix) = ov;
}

// ---------------------------------------------------------------------------
// Kernel 2: one scan-body iteration = 6 fused stencil steps (round-7 proven
// structure; single change: T coefs converted fp16 -> fp32 ONCE at load and
// kept in fp32 registers, removing ~480 per-thread v_cvt ops from the step
// loop). Thread t owns column c = t%76, rows rs..rs+7; x ping-pongs in LDS
// with a streaming 3x3 window. Sigmoid at even sub-steps. Region ring never
// written; contamination <=1 px/step; halo 6 protects the 64x64 core.
// VGPR budget: 80 treg + 9 window + ~10 addr ~= 100 < 128 cap (768,4);
// occupancy unchanged (16 waves/CU -> 1 block/CU) per m69 VGPR steps.
// ---------------------------------------------------------------------------
__global__ __launch_bounds__(NTHR, 4)
void fused6_vstrip_kernel(const float* __restrict__ xin,   // out slot t-1 base
                          const __half2* __restrict__ T,
                          float* __restrict__ xout) {      // out slot t base
    __shared__ float sA[RS * LP];
    __shared__ float sB[RS * LP];

    int tile = blockIdx.x;          // 512 = 8 batches * 8x8 tiles
    int b   = tile >> 6;
    int trr = (tile >> 3) & 7;
    int tcc = tile & 7;
    int ri = trr * TS - H6;
    int rj = tcc * TS - H6;

    const float* xb = xin + (size_t)b * Td * HWc;
    const __half2* Tb = T + (size_t)b * 5 * HWc;
    int tid = threadIdx.x;

    // Stage sA (zeros outside image).
    for (int idx = tid; idx < RS * RS; idx += NTHR) {
        int r = idx / RS, c = idx - r * RS;
        int gi = ri + r, gj = rj + c;
        float v = 0.0f;
        if ((unsigned)gi < (unsigned)Hd && (unsigned)gj < (unsigned)Wd)
            v = xb[gi * Wd + gj];
        sA[r * LP + c] = v;
    }
    // Zero only sB's ring (ring cells are never written by the step loop;
    // interior is fully rewritten each step before being read).
    for (int idx = tid; idx < 4 * RS; idx += NTHR) {
        int side = idx / RS, k = idx - side * RS;
        int r, c;
        if (side == 0)      { r = 0;      c = k; }
        else if (side == 1) { r = RS - 1; c = k; }
        else if (side == 2) { r = k;      c = 0; }
        else                { r = k;      c = RS - 1; }
        sB[r * LP + c] = 0.0f;
    }

    int g  = tid / RS;              // row group 0..9 valid
    int c  = tid - g * RS;          // column 0..75
    int rs = 1 + g * RPG;           // first owned row
    bool colint = (c >= 1) && (c <= RS - 2);
    bool active = (g < NG) && colint;
    int  gj     = rj + c;
    bool colin  = (unsigned)gj < (unsigned)Wd;

    // T coefficients: load fp16 once, convert to fp32 registers once.
    float treg[RPG][10];
    #pragma unroll
    for (int jj = 0; jj < RPG; ++jj) {
        int r  = rs + jj;
        int gi = ri + r;
        bool ok = active && (r <= RS - 2) && ((unsigned)gi < (unsigned)Hd) && colin;
        #pragma unroll
        for (int q = 0; q < 5; ++q) {
            __half2 h = ok ? Tb[(size_t)q * HWc + gi * Wd + gj]
                           : __floats2half2_rn(0.0f, 0.0f);
            float2 f = __half22float2(h);
            treg[jj][2 * q]     = f.x;
            treg[jj][2 * q + 1] = f.y;
        }
    }
    __syncthreads();

    float* cur = sA;
    float* nxt = sB;

    #pragma unroll
    for (int s = 1; s <= 6; ++s) {
        if (active) {
            float w00 = cur[(rs - 1) * LP + c - 1];
            float w01 = cur[(rs - 1) * LP + c];
            float w02 = cur[(rs - 1) * LP + c + 1];
            float w10 = cur[rs * LP + c - 1];
            float w11 = cur[rs * LP + c];
            float w12 = cur[rs * LP + c + 1];
            #pragma unroll
            for (int jj = 0; jj < RPG; ++jj) {
                int r  = rs + jj;
                int r2 = (r + 1 <= RS - 1) ? (r + 1) : (RS - 1);  // clamp (g=9 tail)
                float w20 = cur[r2 * LP + c - 1];
                float w21 = cur[r2 * LP + c];
                float w22 = cur[r2 * LP + c + 1];

                // k = dj*3+di multiplies x[r+di-1][c+dj-1]
                float a = treg[jj][9]
                        + w00 * treg[jj][0] + w10 * treg[jj][1] + w20 * treg[jj][2]
                        + w01 * treg[jj][3] + w11 * treg[jj][4] + w21 * treg[jj][5]
                        + w02 * treg[jj][6] + w12 * treg[jj][7] + w22 * treg[jj][8];
                if ((s & 1) == 0) a = 1.0f / (1.0f + __expf(-a));

                int gi = ri + r;
                bool rowok = (r <= RS - 2);
                bool inimg = ((unsigned)gi < (unsigned)Hd) && colin;
                if (rowok) nxt[r * LP + c] = inimg ? a : 0.0f;

                w00 = w10; w01 = w11; w02 = w12;
                w10 = w20; w11 = w21; w12 = w22;
            }
        }
        __syncthreads();
        float* tmp = cur; cur = nxt; nxt = tmp;
    }

    // After 6 swaps the result is back in sA (== cur). Write 64x64 core.
    float* ob = xout + (size_t)b * Td * HWc;
    for (int idx = tid; idx < TS * TS; idx += NTHR) {
        int rr = idx >> 6, cc = idx & 63;
        ob[(ri + H6 + rr) * Wd + (rj + H6 + cc)] = cur[(H6 + rr) * LP + (H6 + cc)];
    }
}

// ---------------------------------------------------------------------------
// Workspace: T only (B*5*H*W half2 = 40 MB).
// ---------------------------------------------------------------------------
extern "C" void kernel_launch(void* const* d_in, const int* in_sizes, int n_in,
                              void* d_out, int out_size, void* d_ws, size_t ws_size,
                              hipStream_t stream) {
    const float* x  = (const float*)d_in[0];
    const float* Wu = (const float*)d_in[1];
    const float* bu = (const float*)d_in[2];
    float* out = (float*)d_out;
    __half2* T = (__half2*)d_ws;

    conv_step0_kernel<<<2048, CTHR, 0, stream>>>(x, Wu, bu, T, out);

    for (int t = 1; t < Td; ++t)
        fused6_vstrip_kernel<<<512, NTHR, 0, stream>>>(out + (size_t)(t - 1) * HWc, T,
                                                       out + (size_t)t * HWc);
}

// Round 12
// 546.683 us; speedup vs baseline: 1.9683x; 1.1286x over previous
//
#include <hip/hip_runtime.h>
#include <hip/hip_fp16.h>
#include <math.h>

// Problem constants: B=8, Tt=16, C=1, H=W=512, 4 in-channels, 10 T-planes.
#define Bd 8
#define Td 16
#define Hd 512
#define Wd 512
#define HWc (Hd * Wd)          // 262144
#define NPIX (Bd * HWc)        // 2,097,152

// ---------------- conv tiling: 128x16 tile, 4 px/thread (2x2), 512 threads ---
#define VTW 128                // tile cols
#define VTH 16                 // tile rows
#define VRW 130                // region cols
#define VRH 18                 // region rows
#define VP  132                // LDS row pitch (words)
#define VTHR 512

// ---------------- fused-step tiling: 128x64 core, halo 6, round-7 code -------
#define WCR 128                // core rows
#define WCC 64                 // core cols
#define WH  6                  // halo
#define WTR 140                // region rows
#define WTC 76                 // region cols
#define WLP 77                 // LDS row pitch
#define WTHR 1024
#define WRPG 11                // owned rows per thread
#define WNG 13                 // row groups (13*11 = 143 >= 138 interior rows)

// ---------------------------------------------------------------------------
// Kernel 1: tiled conv  T = conv2d(x[:, -4:, 0], W_unet, SAME) + b_unet,
// fused with xt0 = stencil(x[:,15,0], T_fp32) -> out[:, 0].
// 4 px/thread (2 rows x 2 cols) so each uniform weight load feeds 4 FMAs.
// T stored as half2 pairs: plane q holds (T[2q], T[2q+1]); layout (B,5,H,W).
// ---------------------------------------------------------------------------
__global__ __launch_bounds__(VTHR, 4)
void conv_step0_kernel(const float* __restrict__ x,
                       const float* __restrict__ Wu,
                       const float* __restrict__ bu,
                       __half2* __restrict__ T,
                       float* __restrict__ out) {
    __shared__ __align__(16) float sX[4][VRH][VP];   // 38 KB

    int bx  = blockIdx.x;           // 1024 = 8 b * 32 row-bands * 4 col-bands
    int b   = bx >> 7;
    int rem = bx & 127;
    int by  = rem >> 2;             // row band 0..31 (16 rows each)
    int bc  = rem & 3;              // col band 0..3 (128 cols each)
    int i0  = by * VTH;
    int j0  = bc * VTW;

    const float* xb = x + ((size_t)b * Td + 12) * HWc;   // channel c -> slice 12+c
    int tid = threadIdx.x;

    // Stage the 4-channel 18x130 region (zeros outside image).
    for (int idx = tid; idx < 4 * VRH * VRW; idx += VTHR) {
        int ch = idx / (VRH * VRW);
        int r2 = idx - ch * (VRH * VRW);
        int r  = r2 / VRW;
        int c  = r2 - r * VRW;
        int gi = i0 + r - 1, gj = j0 + c - 1;
        float v = 0.0f;
        if ((unsigned)gi < (unsigned)Hd && (unsigned)gj < (unsigned)Wd)
            v = xb[(size_t)ch * HWc + gi * Wd + gj];
        sX[ch][r][c] = v;
    }
    __syncthreads();

    int tx = tid & 63;              // col pair: cols 2tx, 2tx+1
    int ty = tid >> 6;              // row pair: rows 2ty, 2ty+1 (0..7)

    // Accumulators: [row r][col c] for r,c in {0,1}.
    float t00[10], t01[10], t10[10], t11[10];
    #pragma unroll
    for (int o = 0; o < 10; ++o) {
        float bv = bu[o];
        t00[o] = bv; t01[o] = bv; t10[o] = bv; t11[o] = bv;
    }

    // Window: region rows 2ty..2ty+3, region cols 2tx..2tx+3.
    float w[4][4];
    #pragma unroll
    for (int ch = 0; ch < 4; ++ch) {
        #pragma unroll
        for (int rr = 0; rr < 4; ++rr) {
            const float* rp = &sX[ch][2 * ty + rr][2 * tx];
            float2 a  = *(const float2*)rp;
            float2 b2 = *(const float2*)(rp + 2);
            w[rr][0] = a.x; w[rr][1] = a.y; w[rr][2] = b2.x; w[rr][3] = b2.y;
        }
        #pragma unroll
        for (int kh = 0; kh < 3; ++kh) {
            #pragma unroll
            for (int o = 0; o < 10; ++o) {
                float wt0 = Wu[((o * 4 + ch) * 3 + kh) * 3 + 0];
                float wt1 = Wu[((o * 4 + ch) * 3 + kh) * 3 + 1];
                float wt2 = Wu[((o * 4 + ch) * 3 + kh) * 3 + 2];
                t00[o] += w[kh][0] * wt0 + w[kh][1] * wt1 + w[kh][2] * wt2;
                t01[o] += w[kh][1] * wt0 + w[kh][2] * wt1 + w[kh][3] * wt2;
                t10[o] += w[kh + 1][0] * wt0 + w[kh + 1][1] * wt1 + w[kh + 1][2] * wt2;
                t11[o] += w[kh + 1][1] * wt0 + w[kh + 1][2] * wt1 + w[kh + 1][3] * wt2;
            }
        }
    }
    // After the ch loop, w[][] holds channel 3 (= x slice 15) -- reused below.

    int gi0 = i0 + 2 * ty;
    int gj0 = j0 + 2 * tx;
    size_t pix0 = (size_t)gi0 * Wd + gj0;       // even col
    size_t pix1 = pix0 + Wd;
    __half2* Tb = T + (size_t)b * 5 * HWc;
    #pragma unroll
    for (int q = 0; q < 5; ++q) {
        __half2 a0 = __floats2half2_rn(t00[2 * q], t00[2 * q + 1]);
        __half2 a1 = __floats2half2_rn(t01[2 * q], t01[2 * q + 1]);
        __half2 b0 = __floats2half2_rn(t10[2 * q], t10[2 * q + 1]);
        __half2 b1 = __floats2half2_rn(t11[2 * q], t11[2 * q + 1]);
        uint2 p0, p1;
        p0.x = *(unsigned*)&a0; p0.y = *(unsigned*)&a1;
        p1.x = *(unsigned*)&b0; p1.y = *(unsigned*)&b1;
        *(uint2*)(Tb + (size_t)q * HWc + pix0) = p0;
        *(uint2*)(Tb + (size_t)q * HWc + pix1) = p1;
    }

    // step0 on channel 3, fp32 coefficients. k = dj*3+di multiplies
    // x15[i+di-1, j+dj-1] = w[di + row][dj + col].
    float o00 = t00[9], o01 = t01[9], o10 = t10[9], o11 = t11[9];
    #pragma unroll
    for (int dj = 0; dj < 3; ++dj)
        #pragma unroll
        for (int di = 0; di < 3; ++di) {
            int k = dj * 3 + di;
            o00 += w[di][dj]         * t00[k];
            o01 += w[di][dj + 1]     * t01[k];
            o10 += w[di + 1][dj]     * t10[k];
            o11 += w[di + 1][dj + 1] * t11[k];
        }
    float* ob = out + (size_t)b * Td * HWc;
    float2 v0; v0.x = o00; v0.y = o01;
    float2 v1; v1.x = o10; v1.y = o11;
    *(float2*)(ob + pix0) = v0;
    *(float2*)(ob + pix1) = v1;
}

// ---------------------------------------------------------------------------
// Kernel 2: one scan-body iteration = 6 fused stencil steps. Round-7 code
// verbatim; geometry only change: 128x64 core (region 140x76), 1024 threads,
// 256 blocks = 8 b * 4 row-tiles * 8 col-tiles -> exactly 1 block/CU, ONE
// round (was 2 rounds of 256). Thread t owns column c = t%76, rows
// rs..rs+10; 55 half2 T coefs in VGPRs; x ping-pongs in LDS (2 x 43 KB).
// Sigmoid at even sub-steps. Region ring never written; contamination
// <=1 px/step; halo 6 protects the core. VGPR ~90 < 128 cap (1024,4).
// ---------------------------------------------------------------------------
__global__ __launch_bounds__(WTHR, 4)
void fused6_wide_kernel(const float* __restrict__ xin,   // out slot t-1 base
                        const __half2* __restrict__ T,
                        float* __restrict__ xout) {      // out slot t base
    __shared__ float sA[WTR * WLP];
    __shared__ float sB[WTR * WLP];

    int tile = blockIdx.x;          // 256 = 8 b * 4 tr * 8 tc
    int b  = tile >> 5;
    int tr = (tile >> 3) & 3;
    int tc = tile & 7;
    int ri = tr * WCR - WH;
    int rj = tc * WCC - WH;

    const float* xb = xin + (size_t)b * Td * HWc;
    const __half2* Tb = T + (size_t)b * 5 * HWc;
    int tid = threadIdx.x;

    // Stage sA (zeros outside image).
    for (int idx = tid; idx < WTR * WTC; idx += WTHR) {
        int r = idx / WTC, c = idx - r * WTC;
        int gi = ri + r, gj = rj + c;
        float v = 0.0f;
        if ((unsigned)gi < (unsigned)Hd && (unsigned)gj < (unsigned)Wd)
            v = xb[gi * Wd + gj];
        sA[r * WLP + c] = v;
    }
    // Zero only sB's ring (never written by the step loop; interior is fully
    // rewritten each step before being read).
    for (int idx = tid; idx < 2 * WTC; idx += WTHR) {
        int r = (idx < WTC) ? 0 : (WTR - 1);
        int c = (idx < WTC) ? idx : idx - WTC;
        sB[r * WLP + c] = 0.0f;
    }
    for (int idx = tid; idx < 2 * WTR; idx += WTHR) {
        int r = (idx < WTR) ? idx : idx - WTR;
        int c = (idx < WTR) ? 0 : (WTC - 1);
        sB[r * WLP + c] = 0.0f;
    }

    int g  = tid / WTC;             // row group 0..12 valid
    int c  = tid - g * WTC;         // column 0..75
    int rs = 1 + g * WRPG;          // first owned row
    bool colint = (c >= 1) && (c <= WTC - 2);
    bool active = (g < WNG) && colint;
    int  gj     = rj + c;
    bool colin  = (unsigned)gj < (unsigned)Wd;

    // T coefficients: 5 half2 per owned row (round-7 proven register profile).
    __half2 treg[WRPG][5];
    #pragma unroll
    for (int jj = 0; jj < WRPG; ++jj) {
        int r  = rs + jj;
        int gi = ri + r;
        bool ok = active && (r <= WTR - 2) && ((unsigned)gi < (unsigned)Hd) && colin;
        #pragma unroll
        for (int q = 0; q < 5; ++q)
            treg[jj][q] = ok ? Tb[(size_t)q * HWc + gi * Wd + gj]
                             : __floats2half2_rn(0.0f, 0.0f);
    }
    __syncthreads();

    float* cur = sA;
    float* nxt = sB;

    #pragma unroll
    for (int s = 1; s <= 6; ++s) {
        if (active) {
            float w00 = cur[(rs - 1) * WLP + c - 1];
            float w01 = cur[(rs - 1) * WLP + c];
            float w02 = cur[(rs - 1) * WLP + c + 1];
            float w10 = cur[rs * WLP + c - 1];
            float w11 = cur[rs * WLP + c];
            float w12 = cur[rs * WLP + c + 1];
            #pragma unroll
            for (int jj = 0; jj < WRPG; ++jj) {
                int r  = rs + jj;
                int r2 = (r + 1 <= WTR - 1) ? (r + 1) : (WTR - 1);  // clamp tail
                float w20 = cur[r2 * WLP + c - 1];
                float w21 = cur[r2 * WLP + c];
                float w22 = cur[r2 * WLP + c + 1];

                float2 p0 = __half22float2(treg[jj][0]);  // T0,T1
                float2 p1 = __half22float2(treg[jj][1]);  // T2,T3
                float2 p2 = __half22float2(treg[jj][2]);  // T4,T5
                float2 p3 = __half22float2(treg[jj][3]);  // T6,T7
                float2 p4 = __half22float2(treg[jj][4]);  // T8,T9

                // k = dj*3+di multiplies x[r+di-1][c+dj-1]
                float a = p4.y
                        + w00 * p0.x + w10 * p0.y + w20 * p1.x
                        + w01 * p1.y + w11 * p2.x + w21 * p2.y
                        + w02 * p3.x + w12 * p3.y + w22 * p4.x;
                if ((s & 1) == 0) a = 1.0f / (1.0f + __expf(-a));

                int gi = ri + r;
                bool rowok = (r <= WTR - 2);
                bool inimg = ((unsigned)gi < (unsigned)Hd) && colin;
                if (rowok) nxt[r * WLP + c] = inimg ? a : 0.0f;

                w00 = w10; w01 = w11; w02 = w12;
                w10 = w20; w11 = w21; w12 = w22;
            }
        }
        __syncthreads();
        float* tmp = cur; cur = nxt; nxt = tmp;
    }

    // After 6 swaps the result is back in sA (== cur). Write 128x64 core.
    float* ob = xout + (size_t)b * Td * HWc;
    for (int idx = tid; idx < WCR * WCC; idx += WTHR) {
        int rr = idx >> 6, cc = idx & 63;
        ob[(ri + WH + rr) * Wd + (rj + WH + cc)] = cur[(WH + rr) * WLP + (WH + cc)];
    }
}

// ---------------------------------------------------------------------------
// Workspace: T only (B*5*H*W half2 = 40 MB).
// ---------------------------------------------------------------------------
extern "C" void kernel_launch(void* const* d_in, const int* in_sizes, int n_in,
                              void* d_out, int out_size, void* d_ws, size_t ws_size,
                              hipStream_t stream) {
    const float* x  = (const float*)d_in[0];
    const float* Wu = (const float*)d_in[1];
    const float* bu = (const float*)d_in[2];
    float* out = (float*)d_out;
    __half2* T = (__half2*)d_ws;

    conv_step0_kernel<<<1024, VTHR, 0, stream>>>(x, Wu, bu, T, out);

    for (int t = 1; t < Td; ++t)
        fused6_wide_kernel<<<256, WTHR, 0, stream>>>(out + (size_t)(t - 1) * HWc, T,
                                                     out + (size_t)t * HWc);
}